// Round 10
// baseline (572.168 us; speedup 1.0000x reference)
//
#include <hip/hip_runtime.h>
#include <hip/hip_cooperative_groups.h>

#define NN 8192
#define NF 128
#define NH 256
#define NO 128
#define CAP 128   // max nnz per row; E[nnz]=32.8, max over rows ~60
#define RPB 16    // rows per block -> grid 512 = 2 blocks/CU (2x margin vs 5 LDS-allowed)

namespace cg = cooperative_groups;

// ---------------------------------------------------------------------------
// SpMM gather core: half-wave (32 lanes) per row, float4/lane = 512 B/edge,
// 8-deep load pipeline, 2 accumulator sets.
// returns d_i * sum_e coef_e * Y[col_e] + d_i^2 * Y[row]   (per float4 slice)
// ---------------------------------------------------------------------------
__device__ __forceinline__ float4 spmm_row(const float4* __restrict__ Y,
    const float* scoef, const int* soff, int c, int row, int sub, float di) {
  float ax = 0.f, ay = 0.f, az = 0.f, aw = 0.f;
  float bx = 0.f, by = 0.f, bz = 0.f, bw = 0.f;
  int e = 0;
  for (; e + 8 <= c; e += 8) {
    float cc[8];
    float4 y[8];
#pragma unroll
    for (int u = 0; u < 8; ++u) {
      cc[u] = scoef[e + u];
      y[u] = Y[soff[e + u] + sub];
    }
#pragma unroll
    for (int u = 0; u < 8; u += 2) {
      ax = fmaf(cc[u], y[u].x, ax); ay = fmaf(cc[u], y[u].y, ay);
      az = fmaf(cc[u], y[u].z, az); aw = fmaf(cc[u], y[u].w, aw);
      bx = fmaf(cc[u + 1], y[u + 1].x, bx); by = fmaf(cc[u + 1], y[u + 1].y, by);
      bz = fmaf(cc[u + 1], y[u + 1].z, bz); bw = fmaf(cc[u + 1], y[u + 1].w, bw);
    }
  }
  for (; e + 4 <= c; e += 4) {
    float cc[4];
    float4 y[4];
#pragma unroll
    for (int u = 0; u < 4; ++u) {
      cc[u] = scoef[e + u];
      y[u] = Y[soff[e + u] + sub];
    }
    ax = fmaf(cc[0], y[0].x, ax); ay = fmaf(cc[0], y[0].y, ay);
    az = fmaf(cc[0], y[0].z, az); aw = fmaf(cc[0], y[0].w, aw);
    bx = fmaf(cc[1], y[1].x, bx); by = fmaf(cc[1], y[1].y, by);
    bz = fmaf(cc[1], y[1].z, bz); bw = fmaf(cc[1], y[1].w, bw);
    ax = fmaf(cc[2], y[2].x, ax); ay = fmaf(cc[2], y[2].y, ay);
    az = fmaf(cc[2], y[2].z, az); aw = fmaf(cc[2], y[2].w, aw);
    bx = fmaf(cc[3], y[3].x, bx); by = fmaf(cc[3], y[3].y, by);
    bz = fmaf(cc[3], y[3].z, bz); bw = fmaf(cc[3], y[3].w, bw);
  }
  for (; e < c; ++e) {
    float c0 = scoef[e];
    float4 y0 = Y[soff[e] + sub];
    ax = fmaf(c0, y0.x, ax); ay = fmaf(c0, y0.y, ay);
    az = fmaf(c0, y0.z, az); aw = fmaf(c0, y0.w, aw);
  }
  float4 sv = Y[(size_t)row * 32 + sub];
  float dii = di * di;
  float4 r;
  r.x = fmaf(di, ax + bx, dii * sv.x);
  r.y = fmaf(di, ay + by, dii * sv.y);
  r.z = fmaf(di, az + bz, dii * sv.z);
  r.w = fmaf(di, aw + bw, dii * sv.w);
  return r;
}

// ---------------------------------------------------------------------------
// One cooperative kernel, 512 blocks x 256 threads. Block b owns rows
// 16b..16b+15 in every phase (edge lists persistent in LDS).
//  phase0: scan adj (ballot-compact edge lists into LDS), dinv -> global
//  [grid sync]
//  phaseA: per 8-row group g=0,1: spmm(x)->axs(LDS); gemm1->hs(LDS);
//          gemm2 hs@W2 -> hw (global; needed cross-block)
//  [grid sync]
//  phaseB: spmm(hw) + b2 -> out  (reuses persistent LDS coefs)
// ---------------------------------------------------------------------------
__global__ __launch_bounds__(256, 2) void k_fused(
    const float* __restrict__ x, const float* __restrict__ adj,
    const float* __restrict__ W1, const float* __restrict__ b1,
    const float* __restrict__ W2, const float* __restrict__ b2,
    float* __restrict__ out, float* __restrict__ dinv, float* __restrict__ hw) {
  __shared__ int   lcols[RPB][CAP];    // 8 KB: col, then col*32 (soff)
  __shared__ float lvals[RPB][CAP];    // 8 KB: adj val, then val*dinv[col]
  __shared__ float4 axs[8][NF / 4];    // 4 KB spmm1 result (per group)
  __shared__ float4 hs4[8][NH / 4];    // 8 KB h tile (per group)
  __shared__ int   cntN[RPB];
  __shared__ float dinvN[RPB];
  __shared__ int   cnt_s;
  __shared__ float wsum[4];

  int tid = threadIdx.x;
  int lane = tid & 63;
  int wv = tid >> 6;
  int base = blockIdx.x * RPB;
  unsigned long long lmask = (1ull << lane) - 1ull;

  // ---- phase 0: build edge lists (ballot compaction) ----
  for (int r = 0; r < RPB; ++r) {
    int row = base + r;
    if (tid == 0) cnt_s = 0;
    __syncthreads();
    const float4* arow4 = reinterpret_cast<const float4*>(adj + (size_t)row * NN);
    float lsum = 0.f;
#pragma unroll
    for (int k = 0; k < 8; ++k) {
      int idx = k * 256 + tid;
      float4 v = arow4[idx];
      float vv[4] = {v.x, v.y, v.z, v.w};
#pragma unroll
      for (int c4 = 0; c4 < 4; ++c4) {
        float fv = vv[c4];
        lsum += fv;
        unsigned long long m = __ballot(fv != 0.0f);
        if (m) {                                  // wave-uniform branch
          int old = 0;
          if (lane == 0) old = atomicAdd(&cnt_s, __popcll(m));
          old = __shfl(old, 0, 64);
          if (fv != 0.0f) {
            int pos = old + (int)__popcll(m & lmask);
            if (pos < CAP) { lcols[r][pos] = idx * 4 + c4; lvals[r][pos] = fv; }
          }
        }
      }
    }
#pragma unroll
    for (int o = 32; o > 0; o >>= 1) lsum += __shfl_down(lsum, o, 64);
    if (lane == 0) wsum[wv] = lsum;
    __syncthreads();
    if (tid == 0) {
      float tot = wsum[0] + wsum[1] + wsum[2] + wsum[3];
      float di = rsqrtf(1.0f + tot);
      dinv[row] = di; dinvN[r] = di;
      cntN[r] = cnt_s > CAP ? CAP : cnt_s;
    }
    __syncthreads();
  }

  cg::this_grid().sync();

  // ---- stage coefs for all 16 rows (needs cross-block dinv) ----
  int lrow = tid >> 5, sub = tid & 31;
  for (int rr = lrow; rr < RPB; rr += 8) {
    int c = cntN[rr];
    for (int p = sub; p < c; p += 32) {
      int col = lcols[rr][p];
      lvals[rr][p] *= dinv[col];
      lcols[rr][p] = col * 32;         // float4 units (128 f32/row)
    }
  }
  __syncthreads();

  // ---- phase A: per 8-row group: spmm(x) -> gemm1 -> gemm2 -> hw ----
  const float4* x4 = reinterpret_cast<const float4*>(x);
  for (int g = 0; g < 2; ++g) {
    int r = g * 8 + lrow;
    int row = base + r;
    axs[lrow][sub] = spmm_row(x4, lvals[r], lcols[r], cntN[r], row, sub, dinvN[r]);
    __syncthreads();
    {  // gemm1: thread tid -> output col tid for all 8 rows; h stays in LDS
      float acc[8] = {};
      for (int k4 = 0; k4 < NF / 4; ++k4) {
        float4 xv[8];
#pragma unroll
        for (int q = 0; q < 8; ++q) xv[q] = axs[q][k4];
        int k = k4 * 4;
        float wa = W1[(k + 0) * NH + tid];
        float wb = W1[(k + 1) * NH + tid];
        float wc = W1[(k + 2) * NH + tid];
        float wd = W1[(k + 3) * NH + tid];
#pragma unroll
        for (int q = 0; q < 8; ++q)
          acc[q] = fmaf(xv[q].x, wa, fmaf(xv[q].y, wb,
                   fmaf(xv[q].z, wc, fmaf(xv[q].w, wd, acc[q]))));
      }
      float bb = b1[tid];
      float* hsf = reinterpret_cast<float*>(hs4);
#pragma unroll
      for (int q = 0; q < 8; ++q)
        hsf[q * NH + tid] = fmaxf(acc[q] + bb, 0.f);
    }
    __syncthreads();
    {  // gemm2: 128 cols x 2 row-halves -> hw (global)
      int col = tid & 127, rh = tid >> 7;
      float acc2[4] = {};
      for (int k4 = 0; k4 < NH / 4; ++k4) {
        float4 h0 = hs4[rh * 4 + 0][k4];
        float4 h1 = hs4[rh * 4 + 1][k4];
        float4 h2 = hs4[rh * 4 + 2][k4];
        float4 h3 = hs4[rh * 4 + 3][k4];
        int k = k4 * 4;
        float wa = W2[(k + 0) * NO + col];
        float wb = W2[(k + 1) * NO + col];
        float wc = W2[(k + 2) * NO + col];
        float wd = W2[(k + 3) * NO + col];
        acc2[0] = fmaf(h0.x, wa, fmaf(h0.y, wb, fmaf(h0.z, wc, fmaf(h0.w, wd, acc2[0]))));
        acc2[1] = fmaf(h1.x, wa, fmaf(h1.y, wb, fmaf(h1.z, wc, fmaf(h1.w, wd, acc2[1]))));
        acc2[2] = fmaf(h2.x, wa, fmaf(h2.y, wb, fmaf(h2.z, wc, fmaf(h2.w, wd, acc2[2]))));
        acc2[3] = fmaf(h3.x, wa, fmaf(h3.y, wb, fmaf(h3.z, wc, fmaf(h3.w, wd, acc2[3]))));
      }
#pragma unroll
      for (int q = 0; q < 4; ++q)
        hw[(size_t)(base + g * 8 + rh * 4 + q) * NO + col] = acc2[q];
    }
    __syncthreads();
  }

  cg::this_grid().sync();

  // ---- phase B: spmm(hw) + b2 -> out ----
  const float4* hw4 = reinterpret_cast<const float4*>(hw);
  for (int g = 0; g < 2; ++g) {
    int r = g * 8 + lrow;
    int row = base + r;
    float4 rr = spmm_row(hw4, lvals[r], lcols[r], cntN[r], row, sub, dinvN[r]);
    float4 bv = reinterpret_cast<const float4*>(b2)[sub];
    rr.x += bv.x; rr.y += bv.y; rr.z += bv.z; rr.w += bv.w;
    reinterpret_cast<float4*>(out)[(size_t)row * 32 + sub] = rr;
  }
}

extern "C" void kernel_launch(void* const* d_in, const int* in_sizes, int n_in,
                              void* d_out, int out_size, void* d_ws, size_t ws_size,
                              hipStream_t stream) {
  const float* x   = (const float*)d_in[0];
  const float* adj = (const float*)d_in[1];
  const float* W1  = (const float*)d_in[2];
  const float* b1  = (const float*)d_in[3];
  const float* W2  = (const float*)d_in[4];
  const float* b2  = (const float*)d_in[5];
  float* out = (float*)d_out;

  char* ws = (char*)d_ws;
  float* dinv = (float*)ws;                 // 32 KB
  float* hw   = (float*)(ws + 32768);       // 4 MB [NN, NO]

  void* args[] = {(void*)&x, (void*)&adj, (void*)&W1, (void*)&b1,
                  (void*)&W2, (void*)&b2, (void*)&out, (void*)&dinv, (void*)&hw};
  hipLaunchCooperativeKernel((void*)k_fused, dim3(NN / RPB), dim3(256),
                             args, 0, stream);
}

// Round 11
// 411.627 us; speedup vs baseline: 1.3900x; 1.3900x over previous
//
#include <hip/hip_runtime.h>

#define NN 8192
#define NF 128
#define NH 256
#define NO 128
#define CAP 128   // max nnz per row; E[nnz]=32.8, max over rows ~60

// ---------------------------------------------------------------------------
// Kernel 1 (identical to round 7): one pass over dense adj, one block per
// row. Compact nonzeros into edge list, dinv = rsqrt(1 + row_sum).
// 8192 blocks -> full occupancy, ~82-85% HBM BW. Floor: 41 us.
// ---------------------------------------------------------------------------
__global__ __launch_bounds__(256) void k_build(const float* __restrict__ adj,
    int* __restrict__ counts, int* __restrict__ cols, float* __restrict__ vals,
    float* __restrict__ dinv) {
  int row = blockIdx.x;
  const float* arow = adj + (size_t)row * NN;
  __shared__ int cnt;
  __shared__ float wsum[4];
  if (threadIdx.x == 0) cnt = 0;
  __syncthreads();
  int t = threadIdx.x;
  float lsum = 0.f;
#pragma unroll
  for (int k = 0; k < NN / (256 * 4); ++k) {   // 8 iters of float4
    int base = (k * 256 + t) * 4;
    float4 v = *reinterpret_cast<const float4*>(arow + base);
    float vv[4] = {v.x, v.y, v.z, v.w};
#pragma unroll
    for (int c4 = 0; c4 < 4; ++c4) {
      float fv = vv[c4];
      lsum += fv;
      if (fv != 0.0f) {
        int p = atomicAdd(&cnt, 1);
        if (p < CAP) {
          cols[(size_t)row * CAP + p] = base + c4;
          vals[(size_t)row * CAP + p] = fv;
        }
      }
    }
  }
#pragma unroll
  for (int o = 32; o > 0; o >>= 1) lsum += __shfl_down(lsum, o, 64);
  int lane = t & 63, wv = t >> 6;
  if (lane == 0) wsum[wv] = lsum;
  __syncthreads();
  if (t == 0) {
    float tot = wsum[0] + wsum[1] + wsum[2] + wsum[3];
    dinv[row] = rsqrtf(1.0f + tot);
    counts[row] = cnt > CAP ? CAP : cnt;
  }
}

// ---------------------------------------------------------------------------
// SpMM gather core: half-wave (32 lanes) per row, float4/lane = 512 B/edge,
// 8-deep load pipeline, 2 accumulator sets.
// returns d_i * sum_e coef_e * Y[col_e] + d_i^2 * Y[row]   (per float4 slice)
// ---------------------------------------------------------------------------
__device__ __forceinline__ float4 spmm_row(const float4* __restrict__ Y,
    const float* scoef, const int* soff, int c, int row, int sub, float di) {
  float ax = 0.f, ay = 0.f, az = 0.f, aw = 0.f;
  float bx = 0.f, by = 0.f, bz = 0.f, bw = 0.f;
  int e = 0;
  for (; e + 8 <= c; e += 8) {
    float cc[8];
    float4 y[8];
#pragma unroll
    for (int u = 0; u < 8; ++u) {
      cc[u] = scoef[e + u];
      y[u] = Y[soff[e + u] + sub];
    }
#pragma unroll
    for (int u = 0; u < 8; u += 2) {
      ax = fmaf(cc[u], y[u].x, ax); ay = fmaf(cc[u], y[u].y, ay);
      az = fmaf(cc[u], y[u].z, az); aw = fmaf(cc[u], y[u].w, aw);
      bx = fmaf(cc[u + 1], y[u + 1].x, bx); by = fmaf(cc[u + 1], y[u + 1].y, by);
      bz = fmaf(cc[u + 1], y[u + 1].z, bz); bw = fmaf(cc[u + 1], y[u + 1].w, bw);
    }
  }
  for (; e + 4 <= c; e += 4) {
    float cc[4];
    float4 y[4];
#pragma unroll
    for (int u = 0; u < 4; ++u) {
      cc[u] = scoef[e + u];
      y[u] = Y[soff[e + u] + sub];
    }
    ax = fmaf(cc[0], y[0].x, ax); ay = fmaf(cc[0], y[0].y, ay);
    az = fmaf(cc[0], y[0].z, az); aw = fmaf(cc[0], y[0].w, aw);
    bx = fmaf(cc[1], y[1].x, bx); by = fmaf(cc[1], y[1].y, by);
    bz = fmaf(cc[1], y[1].z, bz); bw = fmaf(cc[1], y[1].w, bw);
    ax = fmaf(cc[2], y[2].x, ax); ay = fmaf(cc[2], y[2].y, ay);
    az = fmaf(cc[2], y[2].z, az); aw = fmaf(cc[2], y[2].w, aw);
    bx = fmaf(cc[3], y[3].x, bx); by = fmaf(cc[3], y[3].y, by);
    bz = fmaf(cc[3], y[3].z, bz); bw = fmaf(cc[3], y[3].w, bw);
  }
  for (; e < c; ++e) {
    float c0 = scoef[e];
    float4 y0 = Y[soff[e] + sub];
    ax = fmaf(c0, y0.x, ax); ay = fmaf(c0, y0.y, ay);
    az = fmaf(c0, y0.z, az); aw = fmaf(c0, y0.w, aw);
  }
  float4 sv = Y[(size_t)row * 32 + sub];
  float dii = di * di;
  float4 r;
  r.x = fmaf(di, ax + bx, dii * sv.x);
  r.y = fmaf(di, ay + by, dii * sv.y);
  r.z = fmaf(di, az + bz, dii * sv.z);
  r.w = fmaf(di, aw + bw, dii * sv.w);
  return r;
}

// ---------------------------------------------------------------------------
// Fused layers: hw = relu((An@x)@W1 + b1) @ W2. 8 rows/block, 256 threads,
// 1024 blocks (full occupancy). spmm result and h live only in LDS.
// ---------------------------------------------------------------------------
__global__ __launch_bounds__(256) void k_layer12(const float* __restrict__ xf,
    const int* __restrict__ counts, const int* __restrict__ cols,
    const float* __restrict__ vals, const float* __restrict__ dinv,
    const float* __restrict__ W1, const float* __restrict__ b1,
    const float* __restrict__ W2, float* __restrict__ hw) {
  const float4* __restrict__ Y = reinterpret_cast<const float4*>(xf);
  __shared__ float4 axs[8][NF / 4];    // 4 KB spmm1 result
  __shared__ float4 hs4[8][NH / 4];    // 8 KB h tile
  __shared__ float scoef[8][CAP];      // 4 KB
  __shared__ int soff[8][CAP];         // 4 KB
  int tid = threadIdx.x;
  int lrow = tid >> 5, sub = tid & 31;
  int row = blockIdx.x * 8 + lrow;
  int c = counts[row];
  float di = dinv[row];
  for (int p = sub; p < c; p += 32) {
    int col = cols[(size_t)row * CAP + p];
    scoef[lrow][p] = vals[(size_t)row * CAP + p] * dinv[col];
    soff[lrow][p] = col * 32;          // float4 units (128 f32/row)
  }
  __syncthreads();
  axs[lrow][sub] = spmm_row(Y, scoef[lrow], soff[lrow], c, row, sub, di);
  __syncthreads();
  {  // gemm1: thread tid -> h column tid for all 8 rows; h stays in LDS
    float acc[8] = {};
    for (int k4 = 0; k4 < NF / 4; ++k4) {
      float4 xv[8];
#pragma unroll
      for (int q = 0; q < 8; ++q) xv[q] = axs[q][k4];
      int k = k4 * 4;
      float wa = W1[(k + 0) * NH + tid];
      float wb = W1[(k + 1) * NH + tid];
      float wc = W1[(k + 2) * NH + tid];
      float wd = W1[(k + 3) * NH + tid];
#pragma unroll
      for (int q = 0; q < 8; ++q)
        acc[q] = fmaf(xv[q].x, wa, fmaf(xv[q].y, wb,
                 fmaf(xv[q].z, wc, fmaf(xv[q].w, wd, acc[q]))));
    }
    float bb = b1[tid];
    float* hsf = reinterpret_cast<float*>(hs4);
#pragma unroll
    for (int q = 0; q < 8; ++q)
      hsf[q * NH + tid] = fmaxf(acc[q] + bb, 0.f);
  }
  __syncthreads();
  {  // gemm2: 128 cols x 2 row-halves, from LDS -> hw (global)
    int col = tid & 127, rh = tid >> 7;
    float acc2[4] = {};
    for (int k4 = 0; k4 < NH / 4; ++k4) {
      float4 h0 = hs4[rh * 4 + 0][k4];
      float4 h1 = hs4[rh * 4 + 1][k4];
      float4 h2 = hs4[rh * 4 + 2][k4];
      float4 h3 = hs4[rh * 4 + 3][k4];
      int k = k4 * 4;
      float wa = W2[(k + 0) * NO + col];
      float wb = W2[(k + 1) * NO + col];
      float wc = W2[(k + 2) * NO + col];
      float wd = W2[(k + 3) * NO + col];
      acc2[0] = fmaf(h0.x, wa, fmaf(h0.y, wb, fmaf(h0.z, wc, fmaf(h0.w, wd, acc2[0]))));
      acc2[1] = fmaf(h1.x, wa, fmaf(h1.y, wb, fmaf(h1.z, wc, fmaf(h1.w, wd, acc2[1]))));
      acc2[2] = fmaf(h2.x, wa, fmaf(h2.y, wb, fmaf(h2.z, wc, fmaf(h2.w, wd, acc2[2]))));
      acc2[3] = fmaf(h3.x, wa, fmaf(h3.y, wb, fmaf(h3.z, wc, fmaf(h3.w, wd, acc2[3]))));
    }
    int base = blockIdx.x * 8;
#pragma unroll
    for (int q = 0; q < 4; ++q)
      hw[(size_t)(base + rh * 4 + q) * NO + col] = acc2[q];
  }
}

// ---------------------------------------------------------------------------
// spmm2 (identical to round 7): out = An @ hw + b2, writes d_out.
// ---------------------------------------------------------------------------
__global__ __launch_bounds__(256) void k_spmm_out(const float* __restrict__ Yf,
    const int* __restrict__ counts, const int* __restrict__ cols,
    const float* __restrict__ vals, const float* __restrict__ dinv,
    const float* __restrict__ bias, float* __restrict__ outf) {
  const float4* __restrict__ Y = reinterpret_cast<const float4*>(Yf);
  float4* __restrict__ out = reinterpret_cast<float4*>(outf);
  __shared__ float scoef[8][CAP];
  __shared__ int soff[8][CAP];
  int tid = threadIdx.x;
  int lrow = tid >> 5, sub = tid & 31;
  int row = blockIdx.x * 8 + lrow;
  int c = counts[row];
  float di = dinv[row];
  for (int p = sub; p < c; p += 32) {
    int col = cols[(size_t)row * CAP + p];
    scoef[lrow][p] = vals[(size_t)row * CAP + p] * dinv[col];
    soff[lrow][p] = col * 32;
  }
  __syncthreads();
  float4 r = spmm_row(Y, scoef[lrow], soff[lrow], c, row, sub, di);
  float4 bv = reinterpret_cast<const float4*>(bias)[sub];
  r.x += bv.x; r.y += bv.y; r.z += bv.z; r.w += bv.w;
  out[(size_t)row * 32 + sub] = r;
}

extern "C" void kernel_launch(void* const* d_in, const int* in_sizes, int n_in,
                              void* d_out, int out_size, void* d_ws, size_t ws_size,
                              hipStream_t stream) {
  const float* x   = (const float*)d_in[0];
  const float* adj = (const float*)d_in[1];
  const float* W1  = (const float*)d_in[2];
  const float* b1  = (const float*)d_in[3];
  const float* W2  = (const float*)d_in[4];
  const float* b2  = (const float*)d_in[5];
  float* out = (float*)d_out;

  char* ws = (char*)d_ws;
  float* dinv   = (float*)(ws);
  int*   counts = (int*)(ws + (size_t)NN * 4);
  int*   cols   = (int*)(ws + (size_t)NN * 8);
  float* vals   = (float*)(ws + (size_t)NN * 8 + (size_t)NN * CAP * 4);
  float* hw     = (float*)(ws + (size_t)NN * 8 + (size_t)NN * CAP * 8);  // [NN,NO]

  hipLaunchKernelGGL(k_build, dim3(NN), dim3(256), 0, stream,
                     adj, counts, cols, vals, dinv);
  hipLaunchKernelGGL(k_layer12, dim3(NN / 8), dim3(256), 0, stream,
                     x, counts, cols, vals, dinv, W1, b1, W2, hw);
  hipLaunchKernelGGL(k_spmm_out, dim3(NN / 8), dim3(256), 0, stream,
                     hw, counts, cols, vals, dinv, b2, out);
}